// Round 1
// baseline (176.234 us; speedup 1.0000x reference)
//
#include <hip/hip_runtime.h>
#include <hip/hip_bf16.h>
#include <cmath>

typedef unsigned short u16;
typedef __bf16 bf16x8 __attribute__((ext_vector_type(8)));
typedef float  f32x4  __attribute__((ext_vector_type(4)));
typedef float  f4     __attribute__((ext_vector_type(4)));
typedef u16    us4    __attribute__((ext_vector_type(4)));

#define DEVFN __device__ __forceinline__

static constexpr int Bq = 2, Nq = 2048, Eq = 1024, Hq = 16, Dq = 64;
static constexpr int Mq = Bq * Nq;        // 4096 tokens
static constexpr int CHK = 64;            // attention chunk
static constexpr int NC  = Nq / CHK;      // 32 chunks
static constexpr int BH  = Bq * Hq;       // 32

DEVFN u16 f2b(float f) {                  // f32 -> bf16 (RNE), finite inputs
    union { float f; unsigned int u; } x; x.f = f;
    unsigned int r = x.u + 0x7fffu + ((x.u >> 16) & 1u);
    return (u16)(r >> 16);
}

// ---------------- f32 -> bf16 bulk convert ----------------
__global__ __launch_bounds__(256) void cvt_kernel(const float* __restrict__ src,
                                                  u16* __restrict__ dst, int n4) {
    int i = blockIdx.x * 256 + threadIdx.x;
    if (i < n4) {
        f4 v = *reinterpret_cast<const f4*>(&src[(size_t)i * 4]);
        us4 p; p[0] = f2b(v[0]); p[1] = f2b(v[1]); p[2] = f2b(v[2]); p[3] = f2b(v[3]);
        *reinterpret_cast<us4*>(&dst[(size_t)i * 4]) = p;
    }
}

// ---------------- GEMM: out[m][n] = act(sum_k X[m][k]*W[n][k] + bias[n]) ----------------
// X: bf16 [4096][1024], W: bf16 [1024][1024] (row = out-feature), bias f32.
// WN: write token-major bf16 [4096][1024]
// WT: write head-transposed bf16 [bh][d][N] (for K^T / V^T)
// WF: write f32 token-major (final output)
template<int ACT, bool WN, bool WT, bool WF>
__global__ __launch_bounds__(256)
void gemm_kernel(const u16* __restrict__ X, const u16* __restrict__ W,
                 const float* __restrict__ bias,
                 u16* __restrict__ outN, u16* __restrict__ outT,
                 float* __restrict__ outF)
{
    __shared__ u16 As[128 * 40];   // stride 40 u16 = 80B: 16B-aligned rows, 2-way banks
    __shared__ u16 Bs[128 * 40];
    const int tid  = threadIdx.x;
    const int m0   = blockIdx.y * 128, n0 = blockIdx.x * 128;
    const int wid  = tid >> 6, lane = tid & 63;
    const int wr   = (wid >> 1) * 64, wc = (wid & 1) * 64;
    const int fr   = lane & 15, fq = lane >> 4, fk = fq * 8;
    const int srow = tid >> 3, sc4 = (tid & 7) * 4;

    f32x4 acc[4][4] = {};

    for (int k0 = 0; k0 < 1024; k0 += 32) {
        __syncthreads();
#pragma unroll
        for (int i = 0; i < 4; ++i) {
            int row = srow + i * 32;
            *reinterpret_cast<us4*>(&As[row * 40 + sc4]) =
                *reinterpret_cast<const us4*>(&X[(size_t)(m0 + row) * 1024 + k0 + sc4]);
            *reinterpret_cast<us4*>(&Bs[row * 40 + sc4]) =
                *reinterpret_cast<const us4*>(&W[(size_t)(n0 + row) * 1024 + k0 + sc4]);
        }
        __syncthreads();
        bf16x8 af[4], bfv[4];
#pragma unroll
        for (int mi = 0; mi < 4; ++mi)
            af[mi] = *reinterpret_cast<const bf16x8*>(&As[(wr + mi * 16 + fr) * 40 + fk]);
#pragma unroll
        for (int ni = 0; ni < 4; ++ni)
            bfv[ni] = *reinterpret_cast<const bf16x8*>(&Bs[(wc + ni * 16 + fr) * 40 + fk]);
#pragma unroll
        for (int mi = 0; mi < 4; ++mi)
#pragma unroll
            for (int ni = 0; ni < 4; ++ni)
                acc[mi][ni] = __builtin_amdgcn_mfma_f32_16x16x32_bf16(
                    af[mi], bfv[ni], acc[mi][ni], 0, 0, 0);
    }

#pragma unroll
    for (int mi = 0; mi < 4; ++mi)
#pragma unroll
        for (int ni = 0; ni < 4; ++ni) {
            const int n     = n0 + wc + ni * 16 + fr;
            const int mbase = m0 + wr + mi * 16 + fq * 4;
            const float bn  = bias[n];
            float vr[4];
#pragma unroll
            for (int r = 0; r < 4; ++r) {
                float v = acc[mi][ni][r] + bn;
                if (ACT == 1) v = (v > 0.f) ? (v + 1.f) : __expf(v);  // elu(v)+1
                vr[r] = v;
            }
            if (WN) {
#pragma unroll
                for (int r = 0; r < 4; ++r)
                    outN[(size_t)(mbase + r) * 1024 + n] = f2b(vr[r]);
            }
            if (WF) {
#pragma unroll
                for (int r = 0; r < 4; ++r)
                    outF[(size_t)(mbase + r) * 1024 + n] = vr[r];
            }
            if (WT) {  // [ (b*16+h)*64 + dd ][ token-in-seq ], 4 consecutive tokens
                us4 pk;
#pragma unroll
                for (int r = 0; r < 4; ++r) pk[r] = f2b(vr[r]);
                const int bb = mbase >> 11, nt = mbase & 2047;
                const int hh = n >> 6,      dd = n & 63;
                *reinterpret_cast<us4*>(
                    &outT[((size_t)(bb * 16 + hh) * 64 + dd) * 2048 + nt]) = pk;
            }
        }
}

// ---------------- per-chunk KV = k_chunk^T @ v_chunk (64x64 f32) ----------------
__global__ __launch_bounds__(64)
void chunk_kv_kernel(const u16* __restrict__ KbT, const u16* __restrict__ VbT,
                     float* __restrict__ KV)
{
    const int blk = blockIdx.x;          // bh*NC + c
    const int bh = blk >> 5, c = blk & 31;
    const int lane = threadIdx.x;
    const int fr = lane & 15, fq = lane >> 4, fk = fq * 8;
    const u16* kt = KbT + (size_t)bh * 64 * 2048;
    const u16* vt = VbT + (size_t)bh * 64 * 2048;

    bf16x8 a[4][2], b[4][2];
#pragma unroll
    for (int mi = 0; mi < 4; ++mi)
#pragma unroll
        for (int kh = 0; kh < 2; ++kh)
            a[mi][kh] = *reinterpret_cast<const bf16x8*>(
                &kt[(size_t)(mi * 16 + fr) * 2048 + c * 64 + kh * 32 + fk]);
#pragma unroll
    for (int ni = 0; ni < 4; ++ni)
#pragma unroll
        for (int kh = 0; kh < 2; ++kh)
            b[ni][kh] = *reinterpret_cast<const bf16x8*>(
                &vt[(size_t)(ni * 16 + fr) * 2048 + c * 64 + kh * 32 + fk]);

    f32x4 acc[4][4] = {};
#pragma unroll
    for (int mi = 0; mi < 4; ++mi)
#pragma unroll
        for (int ni = 0; ni < 4; ++ni)
#pragma unroll
            for (int kh = 0; kh < 2; ++kh)
                acc[mi][ni] = __builtin_amdgcn_mfma_f32_16x16x32_bf16(
                    a[mi][kh], b[ni][kh], acc[mi][ni], 0, 0, 0);

    float* out = KV + (size_t)blk * 4096;   // [dk][de]
#pragma unroll
    for (int mi = 0; mi < 4; ++mi)
#pragma unroll
        for (int ni = 0; ni < 4; ++ni)
#pragma unroll
            for (int r = 0; r < 4; ++r)
                out[(mi * 16 + fq * 4 + r) * 64 + ni * 16 + fr] = acc[mi][ni][r];
}

// ---------------- exclusive scan over chunks; writes bf16 ST^T [de][dk] ----------------
__global__ __launch_bounds__(256)
void scan_kernel(const float* __restrict__ KV, u16* __restrict__ STb)
{
    __shared__ float tile[64 * 65];
    const int bh = blockIdx.x, tid = threadIdx.x;
    float run[16];
#pragma unroll
    for (int i = 0; i < 16; ++i) run[i] = 0.f;

    for (int c = 0; c < NC; ++c) {
        const float* src = KV  + ((size_t)(bh * NC + c)) * 4096;
        u16*         dst = STb + ((size_t)(bh * NC + c)) * 4096;
#pragma unroll
        for (int i = 0; i < 16; ++i) {
            int el = tid + i * 256;          // el = dk*64 + de
            int dk = el >> 6, de = el & 63;
            tile[de * 65 + dk] = run[i];     // transposed: exclusive prefix
            run[i] += src[el];
        }
        __syncthreads();
#pragma unroll
        for (int i = 0; i < 16; ++i) {
            int el = tid + i * 256;          // STb el = de*64 + dk
            dst[el] = f2b(tile[(el >> 6) * 65 + (el & 63)]);
        }
        __syncthreads();
    }
}

// ---------------- per-chunk attention output ----------------
__global__ __launch_bounds__(64)
void attn_kernel(const u16* __restrict__ Qb, const u16* __restrict__ Kb,
                 const u16* __restrict__ VbT, const u16* __restrict__ STb,
                 u16* __restrict__ Ob)
{
    __shared__ u16 P[64 * 72];   // stride 72 u16 = 144B: 16B-aligned, 2-way banks
    const int blk = blockIdx.x;
    const int bh = blk >> 5, c = blk & 31;
    const int b = bh >> 4, h = bh & 15;
    const int lane = threadIdx.x;
    const int fr = lane & 15, fq = lane >> 4, fk = fq * 8;
    const int tok0 = b * 2048 + c * 64;

    bf16x8 qa[4][2];
#pragma unroll
    for (int mi = 0; mi < 4; ++mi)
#pragma unroll
        for (int kh = 0; kh < 2; ++kh)
            qa[mi][kh] = *reinterpret_cast<const bf16x8*>(
                &Qb[(size_t)(tok0 + mi * 16 + fr) * 1024 + h * 64 + kh * 32 + fk]);

    // P = q @ k^T, causal mask, to LDS as bf16
    {
        bf16x8 kb[4][2];
#pragma unroll
        for (int si = 0; si < 4; ++si)
#pragma unroll
            for (int kh = 0; kh < 2; ++kh)
                kb[si][kh] = *reinterpret_cast<const bf16x8*>(
                    &Kb[(size_t)(tok0 + si * 16 + fr) * 1024 + h * 64 + kh * 32 + fk]);
        f32x4 p[4][4] = {};
#pragma unroll
        for (int mi = 0; mi < 4; ++mi)
#pragma unroll
            for (int si = 0; si < 4; ++si)
#pragma unroll
                for (int kh = 0; kh < 2; ++kh)
                    p[mi][si] = __builtin_amdgcn_mfma_f32_16x16x32_bf16(
                        qa[mi][kh], kb[si][kh], p[mi][si], 0, 0, 0);
#pragma unroll
        for (int mi = 0; mi < 4; ++mi)
#pragma unroll
            for (int si = 0; si < 4; ++si)
#pragma unroll
                for (int r = 0; r < 4; ++r) {
                    int t = mi * 16 + fq * 4 + r;
                    int s = si * 16 + fr;
                    float v = (s <= t) ? p[mi][si][r] : 0.0f;
                    P[t * 72 + s] = f2b(v);
                }
    }
    __syncthreads();

    f32x4 acc[4][4] = {};
    // acc = q @ ST   (ST stored transposed: STb[de][dk] = S[dk][de])
    {
        const u16* st = STb + (size_t)blk * 4096;
        bf16x8 sb[4][2];
#pragma unroll
        for (int ni = 0; ni < 4; ++ni)
#pragma unroll
            for (int kh = 0; kh < 2; ++kh)
                sb[ni][kh] = *reinterpret_cast<const bf16x8*>(
                    &st[(ni * 16 + fr) * 64 + kh * 32 + fk]);
#pragma unroll
        for (int mi = 0; mi < 4; ++mi)
#pragma unroll
            for (int ni = 0; ni < 4; ++ni)
#pragma unroll
                for (int kh = 0; kh < 2; ++kh)
                    acc[mi][ni] = __builtin_amdgcn_mfma_f32_16x16x32_bf16(
                        qa[mi][kh], sb[ni][kh], acc[mi][ni], 0, 0, 0);
    }
    // acc += P @ v
    {
        const u16* vt = VbT + (size_t)bh * 64 * 2048;
#pragma unroll
        for (int sh = 0; sh < 2; ++sh) {
            bf16x8 pa[4], vb[4];
#pragma unroll
            for (int mi = 0; mi < 4; ++mi)
                pa[mi] = *reinterpret_cast<const bf16x8*>(
                    &P[(mi * 16 + fr) * 72 + sh * 32 + fk]);
#pragma unroll
            for (int ni = 0; ni < 4; ++ni)
                vb[ni] = *reinterpret_cast<const bf16x8*>(
                    &vt[(size_t)(ni * 16 + fr) * 2048 + c * 64 + sh * 32 + fk]);
#pragma unroll
            for (int mi = 0; mi < 4; ++mi)
#pragma unroll
                for (int ni = 0; ni < 4; ++ni)
                    acc[mi][ni] = __builtin_amdgcn_mfma_f32_16x16x32_bf16(
                        pa[mi], vb[ni], acc[mi][ni], 0, 0, 0);
        }
    }
    // write token-major bf16 O
#pragma unroll
    for (int mi = 0; mi < 4; ++mi)
#pragma unroll
        for (int ni = 0; ni < 4; ++ni)
#pragma unroll
            for (int r = 0; r < 4; ++r) {
                int t = tok0 + mi * 16 + fq * 4 + r;
                int n = h * 64 + ni * 16 + fr;
                Ob[(size_t)t * 1024 + n] = f2b(acc[mi][ni][r]);
            }
}

extern "C" void kernel_launch(void* const* d_in, const int* in_sizes, int n_in,
                              void* d_out, int out_size, void* d_ws, size_t ws_size,
                              hipStream_t stream)
{
    (void)in_sizes; (void)n_in; (void)out_size; (void)ws_size;
    const float* x  = (const float*)d_in[0];
    const float* Wq = (const float*)d_in[1];
    const float* bq = (const float*)d_in[2];
    const float* Wk = (const float*)d_in[3];
    const float* bk = (const float*)d_in[4];
    const float* Wv = (const float*)d_in[5];
    const float* bv = (const float*)d_in[6];
    const float* Wo = (const float*)d_in[7];
    const float* bo = (const float*)d_in[8];
    float* out = (float*)d_out;

    char* ws = (char*)d_ws;
    constexpr size_t SZ_ME = (size_t)Mq * Eq * 2;        // 8 MB
    u16*   Qb  = (u16*)  (ws + 0 * SZ_ME);
    u16*   Kb  = (u16*)  (ws + 1 * SZ_ME);
    u16*   KbT = (u16*)  (ws + 2 * SZ_ME);
    u16*   VbT = (u16*)  (ws + 3 * SZ_ME);
    u16*   Ob  = (u16*)  (ws + 4 * SZ_ME);
    float* KV  = (float*)(ws + 5 * SZ_ME);               // 16 MB f32
    u16*   STb = (u16*)  (ws + 5 * SZ_ME + (size_t)BH * NC * 4096 * 4);
    u16*   Xb  = (u16*)  (ws + 6 * SZ_ME + (size_t)BH * NC * 4096 * 4);
    u16*   Wb0 = (u16*)  (ws + 7 * SZ_ME + (size_t)BH * NC * 4096 * 4);
    u16* Wqb = Wb0;
    u16* Wkb = Wb0 + (size_t)Eq * Eq;
    u16* Wvb = Wb0 + (size_t)2 * Eq * Eq;
    u16* Wob = Wb0 + (size_t)3 * Eq * Eq;

    // 1) bf16 conversions
    {
        int n4x = Mq * Eq / 4;               // 1,048,576
        cvt_kernel<<<dim3((n4x + 255) / 256), dim3(256), 0, stream>>>(x, Xb, n4x);
        int n4w = Eq * Eq / 4;               // 262,144
        cvt_kernel<<<dim3((n4w + 255) / 256), dim3(256), 0, stream>>>(Wq, Wqb, n4w);
        cvt_kernel<<<dim3((n4w + 255) / 256), dim3(256), 0, stream>>>(Wk, Wkb, n4w);
        cvt_kernel<<<dim3((n4w + 255) / 256), dim3(256), 0, stream>>>(Wv, Wvb, n4w);
        cvt_kernel<<<dim3((n4w + 255) / 256), dim3(256), 0, stream>>>(Wo, Wob, n4w);
    }

    dim3 gg(8, 32), gb(256);
    // 2) projections
    gemm_kernel<1, true,  false, false><<<gg, gb, 0, stream>>>(Xb, Wqb, bq, Qb, nullptr, nullptr);
    gemm_kernel<1, true,  true,  false><<<gg, gb, 0, stream>>>(Xb, Wkb, bk, Kb, KbT, nullptr);
    gemm_kernel<0, false, true,  false><<<gg, gb, 0, stream>>>(Xb, Wvb, bv, nullptr, VbT, nullptr);

    // 3) attention
    chunk_kv_kernel<<<dim3(BH * NC), dim3(64), 0, stream>>>(KbT, VbT, KV);
    scan_kernel<<<dim3(BH), dim3(256), 0, stream>>>(KV, STb);
    attn_kernel<<<dim3(BH * NC), dim3(64), 0, stream>>>(Qb, Kb, VbT, STb, Ob);

    // 4) output projection (f32 out)
    gemm_kernel<0, false, false, true><<<gg, gb, 0, stream>>>(Ob, Wob, bo, nullptr, nullptr, out);
}

// Round 2
// 121.405 us; speedup vs baseline: 1.4516x; 1.4516x over previous
//
#include <hip/hip_runtime.h>
#include <hip/hip_bf16.h>
#include <cmath>

typedef unsigned short u16;
typedef __bf16 bf16x8 __attribute__((ext_vector_type(8)));
typedef float  f32x4  __attribute__((ext_vector_type(4)));
typedef float  f4     __attribute__((ext_vector_type(4)));
typedef u16    us4    __attribute__((ext_vector_type(4)));

#define DEVFN __device__ __forceinline__

static constexpr int Bq = 2, Nq = 2048, Eq = 1024;
static constexpr int Mq = Bq * Nq;        // 4096 tokens
static constexpr int CHK = 64;            // attention chunk
static constexpr int NC  = Nq / CHK;      // 32 chunks
static constexpr int BH  = Bq * 16;       // 32

DEVFN u16 f2b(float f) {                  // f32 -> bf16 (RNE), finite inputs
    union { float f; unsigned int u; } x; x.f = f;
    unsigned int r = x.u + 0x7fffu + ((x.u >> 16) & 1u);
    return (u16)(r >> 16);
}

DEVFN void gl_lds16(const u16* g, u16* l) {  // async 16B global->LDS (dest: wave base + lane*16)
    __builtin_amdgcn_global_load_lds(
        (const __attribute__((address_space(1))) unsigned int*)(g),
        (__attribute__((address_space(3))) unsigned int*)(l),
        16, 0, 0);
}

// ---------------- f32 -> bf16 bulk converts ----------------
__global__ __launch_bounds__(256) void cvt_kernel(const float* __restrict__ src,
                                                  u16* __restrict__ dst, int n4) {
    int i = blockIdx.x * 256 + threadIdx.x;
    if (i < n4) {
        f4 v = *reinterpret_cast<const f4*>(&src[(size_t)i * 4]);
        us4 p; p[0] = f2b(v[0]); p[1] = f2b(v[1]); p[2] = f2b(v[2]); p[3] = f2b(v[3]);
        *reinterpret_cast<us4*>(&dst[(size_t)i * 4]) = p;
    }
}

// 4 weight matrices -> one contiguous bf16 buffer [Wq|Wk|Wv|Wo]
__global__ __launch_bounds__(256) void cvt4_kernel(const float* __restrict__ s0,
                                                   const float* __restrict__ s1,
                                                   const float* __restrict__ s2,
                                                   const float* __restrict__ s3,
                                                   u16* __restrict__ dst, int n4each) {
    const int which = blockIdx.y;
    const float* s = (which == 0) ? s0 : (which == 1) ? s1 : (which == 2) ? s2 : s3;
    int i = blockIdx.x * 256 + threadIdx.x;
    if (i < n4each) {
        f4 v = *reinterpret_cast<const f4*>(&s[(size_t)i * 4]);
        us4 p; p[0] = f2b(v[0]); p[1] = f2b(v[1]); p[2] = f2b(v[2]); p[3] = f2b(v[3]);
        *reinterpret_cast<us4*>(&dst[((size_t)which * n4each + i) * 4]) = p;
    }
}

// ---------------- m97-structure GEMM: 128x128 tile, BK=32, global_load_lds w16 ----------------
// out[m][n] = act(sum_k X[m][k]*W[n][k] + bias[n])
// MODE 0: fused QKV (N=3072). seg=n0>>10: 0=q (elu+1 -> Qb), 1=k (elu+1 -> Kb + KbT), 2=v (-> VbT)
// MODE 1: O-projection, f32 token-major output.
template<int MODE>
__global__ __launch_bounds__(256)
void gemm_kernel(const u16* __restrict__ X, const u16* __restrict__ W,
                 const float* __restrict__ b0, const float* __restrict__ b1,
                 const float* __restrict__ b2,
                 u16* __restrict__ Qb, u16* __restrict__ Kb, u16* __restrict__ KbT,
                 u16* __restrict__ VbT, float* __restrict__ outF)
{
    __shared__ u16 As[128 * 32];   // linear (global_load_lds requires contiguous dest)
    __shared__ u16 Bs[128 * 32];
    const int tid  = threadIdx.x;
    const int m0   = blockIdx.y * 128, n0 = blockIdx.x * 128;
    const int wid  = tid >> 6, lane = tid & 63;
    const int wr   = (wid >> 1) * 64, wc = (wid & 1) * 64;
    const int fr   = lane & 15, fq = lane >> 4, fk = fq * 8;

    // staging: thread t covers 16B = 8 u16; row = t/4 (within 64-row half), colq = t%4
    const int srow = tid >> 2, scol = (tid & 3) * 8;
    const u16* gA = X + (size_t)(m0 + srow) * 1024 + scol;
    const u16* gB = W + (size_t)(n0 + srow) * 1024 + scol;
    u16* lA = As + wid * 512;      // wave-uniform base: wid*1024B (16 rows/wave)
    u16* lB = Bs + wid * 512;

    f32x4 acc[4][4] = {};

    for (int k0 = 0; k0 < 1024; k0 += 32) {
        __syncthreads();                         // prior ds_reads done before overwrite
        gl_lds16(gA + k0,             lA);
        gl_lds16(gA + k0 + 64 * 1024, lA + 2048);
        gl_lds16(gB + k0,             lB);
        gl_lds16(gB + k0 + 64 * 1024, lB + 2048);
        __syncthreads();                         // vmcnt(0) drained before barrier

        bf16x8 af[4], bfv[4];
#pragma unroll
        for (int mi = 0; mi < 4; ++mi)
            af[mi] = *reinterpret_cast<const bf16x8*>(&As[(wr + mi * 16 + fr) * 32 + fk]);
#pragma unroll
        for (int ni = 0; ni < 4; ++ni)
            bfv[ni] = *reinterpret_cast<const bf16x8*>(&Bs[(wc + ni * 16 + fr) * 32 + fk]);
#pragma unroll
        for (int mi = 0; mi < 4; ++mi)
#pragma unroll
            for (int ni = 0; ni < 4; ++ni)
                acc[mi][ni] = __builtin_amdgcn_mfma_f32_16x16x32_bf16(
                    af[mi], bfv[ni], acc[mi][ni], 0, 0, 0);
    }

    if (MODE == 0) {
        const int seg = n0 >> 10;                          // 0=q 1=k 2=v (128 | 1024)
        const float* bp = (seg == 0) ? b0 : (seg == 1) ? b1 : b2;
#pragma unroll
        for (int mi = 0; mi < 4; ++mi)
#pragma unroll
            for (int ni = 0; ni < 4; ++ni) {
                const int nl    = (n0 & 1023) + wc + ni * 16 + fr;   // 0..1023 within seg
                const int mbase = m0 + wr + mi * 16 + fq * 4;
                const float bn  = bp[nl];
                float vr[4];
#pragma unroll
                for (int r = 0; r < 4; ++r) {
                    float v = acc[mi][ni][r] + bn;
                    if (seg < 2) v = (v > 0.f) ? (v + 1.f) : __expf(v);  // elu+1
                    vr[r] = v;
                }
                if (seg == 0) {
#pragma unroll
                    for (int r = 0; r < 4; ++r)
                        Qb[(size_t)(mbase + r) * 1024 + nl] = f2b(vr[r]);
                } else {
                    us4 pk;
#pragma unroll
                    for (int r = 0; r < 4; ++r) pk[r] = f2b(vr[r]);
                    const int bb = mbase >> 11, nt = mbase & 2047;
                    const int hh = nl >> 6,     dd = nl & 63;
                    u16* T = (seg == 1) ? KbT : VbT;
                    *reinterpret_cast<us4*>(
                        &T[((size_t)(bb * 16 + hh) * 64 + dd) * 2048 + nt]) = pk;
                    if (seg == 1) {
#pragma unroll
                        for (int r = 0; r < 4; ++r)
                            Kb[(size_t)(mbase + r) * 1024 + nl] = f2b(vr[r]);
                    }
                }
            }
    } else {
#pragma unroll
        for (int mi = 0; mi < 4; ++mi)
#pragma unroll
            for (int ni = 0; ni < 4; ++ni) {
                const int n     = n0 + wc + ni * 16 + fr;
                const int mbase = m0 + wr + mi * 16 + fq * 4;
                const float bn  = b0[n];
#pragma unroll
                for (int r = 0; r < 4; ++r)
                    outF[(size_t)(mbase + r) * 1024 + n] = acc[mi][ni][r] + bn;
            }
    }
}

// ---------------- per-chunk KV = k_chunk^T @ v_chunk (64x64 f32) ----------------
__global__ __launch_bounds__(64)
void chunk_kv_kernel(const u16* __restrict__ KbT, const u16* __restrict__ VbT,
                     float* __restrict__ KV)
{
    const int blk = blockIdx.x;          // bh*NC + c
    const int bh = blk >> 5, c = blk & 31;
    const int lane = threadIdx.x;
    const int fr = lane & 15, fq = lane >> 4, fk = fq * 8;
    const u16* kt = KbT + (size_t)bh * 64 * 2048;
    const u16* vt = VbT + (size_t)bh * 64 * 2048;

    bf16x8 a[4][2], b[4][2];
#pragma unroll
    for (int mi = 0; mi < 4; ++mi)
#pragma unroll
        for (int kh = 0; kh < 2; ++kh)
            a[mi][kh] = *reinterpret_cast<const bf16x8*>(
                &kt[(size_t)(mi * 16 + fr) * 2048 + c * 64 + kh * 32 + fk]);
#pragma unroll
    for (int ni = 0; ni < 4; ++ni)
#pragma unroll
        for (int kh = 0; kh < 2; ++kh)
            b[ni][kh] = *reinterpret_cast<const bf16x8*>(
                &vt[(size_t)(ni * 16 + fr) * 2048 + c * 64 + kh * 32 + fk]);

    f32x4 acc[4][4] = {};
#pragma unroll
    for (int mi = 0; mi < 4; ++mi)
#pragma unroll
        for (int ni = 0; ni < 4; ++ni)
#pragma unroll
            for (int kh = 0; kh < 2; ++kh)
                acc[mi][ni] = __builtin_amdgcn_mfma_f32_16x16x32_bf16(
                    a[mi][kh], b[ni][kh], acc[mi][ni], 0, 0, 0);

    float* out = KV + (size_t)blk * 4096;   // [dk][de]
#pragma unroll
    for (int mi = 0; mi < 4; ++mi)
#pragma unroll
        for (int ni = 0; ni < 4; ++ni)
#pragma unroll
            for (int r = 0; r < 4; ++r)
                out[(mi * 16 + fq * 4 + r) * 64 + ni * 16 + fr] = acc[mi][ni][r];
}

// ---------------- exclusive scan over chunks; writes bf16 ST^T [de][dk] ----------------
__global__ __launch_bounds__(256)
void scan_kernel(const float* __restrict__ KV, u16* __restrict__ STb)
{
    __shared__ float tile[64 * 65];
    const int bh = blockIdx.x, tid = threadIdx.x;
    float run[16];
#pragma unroll
    for (int i = 0; i < 16; ++i) run[i] = 0.f;

    for (int c = 0; c < NC; ++c) {
        const float* src = KV  + ((size_t)(bh * NC + c)) * 4096;
        u16*         dst = STb + ((size_t)(bh * NC + c)) * 4096;
#pragma unroll
        for (int i = 0; i < 16; ++i) {
            int el = tid + i * 256;          // el = dk*64 + de
            int dk = el >> 6, de = el & 63;
            tile[de * 65 + dk] = run[i];     // transposed exclusive prefix
            run[i] += src[el];
        }
        __syncthreads();
#pragma unroll
        for (int i = 0; i < 16; ++i) {
            int el = tid + i * 256;          // STb el = de*64 + dk
            dst[el] = f2b(tile[(el >> 6) * 65 + (el & 63)]);
        }
        __syncthreads();
    }
}

// ---------------- per-chunk attention output ----------------
__global__ __launch_bounds__(64)
void attn_kernel(const u16* __restrict__ Qb, const u16* __restrict__ Kb,
                 const u16* __restrict__ VbT, const u16* __restrict__ STb,
                 u16* __restrict__ Ob)
{
    __shared__ u16 P[64 * 72];   // stride 72 u16 = 144B: 16B-aligned, 2-way banks
    const int blk = blockIdx.x;
    const int bh = blk >> 5, c = blk & 31;
    const int b = bh >> 4, h = bh & 15;
    const int lane = threadIdx.x;
    const int fr = lane & 15, fq = lane >> 4, fk = fq * 8;
    const int tok0 = b * 2048 + c * 64;

    bf16x8 qa[4][2];
#pragma unroll
    for (int mi = 0; mi < 4; ++mi)
#pragma unroll
        for (int kh = 0; kh < 2; ++kh)
            qa[mi][kh] = *reinterpret_cast<const bf16x8*>(
                &Qb[(size_t)(tok0 + mi * 16 + fr) * 1024 + h * 64 + kh * 32 + fk]);

    // P = causal-mask(q @ k^T) -> LDS bf16
    {
        bf16x8 kb[4][2];
#pragma unroll
        for (int si = 0; si < 4; ++si)
#pragma unroll
            for (int kh = 0; kh < 2; ++kh)
                kb[si][kh] = *reinterpret_cast<const bf16x8*>(
                    &Kb[(size_t)(tok0 + si * 16 + fr) * 1024 + h * 64 + kh * 32 + fk]);
        f32x4 p[4][4] = {};
#pragma unroll
        for (int mi = 0; mi < 4; ++mi)
#pragma unroll
            for (int si = 0; si < 4; ++si)
#pragma unroll
                for (int kh = 0; kh < 2; ++kh)
                    p[mi][si] = __builtin_amdgcn_mfma_f32_16x16x32_bf16(
                        qa[mi][kh], kb[si][kh], p[mi][si], 0, 0, 0);
#pragma unroll
        for (int mi = 0; mi < 4; ++mi)
#pragma unroll
            for (int si = 0; si < 4; ++si)
#pragma unroll
                for (int r = 0; r < 4; ++r) {
                    int t = mi * 16 + fq * 4 + r;
                    int s = si * 16 + fr;
                    float v = (s <= t) ? p[mi][si][r] : 0.0f;
                    P[t * 72 + s] = f2b(v);
                }
    }
    __syncthreads();

    f32x4 acc[4][4] = {};
    // acc = q @ ST   (ST stored transposed: STb[de][dk])
    {
        const u16* st = STb + (size_t)blk * 4096;
        bf16x8 sb[4][2];
#pragma unroll
        for (int ni = 0; ni < 4; ++ni)
#pragma unroll
            for (int kh = 0; kh < 2; ++kh)
                sb[ni][kh] = *reinterpret_cast<const bf16x8*>(
                    &st[(ni * 16 + fr) * 64 + kh * 32 + fk]);
#pragma unroll
        for (int mi = 0; mi < 4; ++mi)
#pragma unroll
            for (int ni = 0; ni < 4; ++ni)
#pragma unroll
                for (int kh = 0; kh < 2; ++kh)
                    acc[mi][ni] = __builtin_amdgcn_mfma_f32_16x16x32_bf16(
                        qa[mi][kh], sb[ni][kh], acc[mi][ni], 0, 0, 0);
    }
    // acc += P @ v
    {
        const u16* vt = VbT + (size_t)bh * 64 * 2048;
#pragma unroll
        for (int sh = 0; sh < 2; ++sh) {
            bf16x8 pa[4], vb[4];
#pragma unroll
            for (int mi = 0; mi < 4; ++mi)
                pa[mi] = *reinterpret_cast<const bf16x8*>(
                    &P[(mi * 16 + fr) * 72 + sh * 32 + fk]);
#pragma unroll
            for (int ni = 0; ni < 4; ++ni)
                vb[ni] = *reinterpret_cast<const bf16x8*>(
                    &vt[(size_t)(ni * 16 + fr) * 2048 + c * 64 + sh * 32 + fk]);
#pragma unroll
            for (int mi = 0; mi < 4; ++mi)
#pragma unroll
                for (int ni = 0; ni < 4; ++ni)
                    acc[mi][ni] = __builtin_amdgcn_mfma_f32_16x16x32_bf16(
                        pa[mi], vb[ni], acc[mi][ni], 0, 0, 0);
        }
    }
    // write token-major bf16 O
#pragma unroll
    for (int mi = 0; mi < 4; ++mi)
#pragma unroll
        for (int ni = 0; ni < 4; ++ni)
#pragma unroll
            for (int r = 0; r < 4; ++r) {
                int t = tok0 + mi * 16 + fq * 4 + r;
                int n = h * 64 + ni * 16 + fr;
                Ob[(size_t)t * 1024 + n] = f2b(acc[mi][ni][r]);
            }
}

extern "C" void kernel_launch(void* const* d_in, const int* in_sizes, int n_in,
                              void* d_out, int out_size, void* d_ws, size_t ws_size,
                              hipStream_t stream)
{
    (void)in_sizes; (void)n_in; (void)out_size; (void)ws_size;
    const float* x  = (const float*)d_in[0];
    const float* Wq = (const float*)d_in[1];
    const float* bq = (const float*)d_in[2];
    const float* Wk = (const float*)d_in[3];
    const float* bk = (const float*)d_in[4];
    const float* Wv = (const float*)d_in[5];
    const float* bv = (const float*)d_in[6];
    const float* Wo = (const float*)d_in[7];
    const float* bo = (const float*)d_in[8];
    float* out = (float*)d_out;

    char* ws = (char*)d_ws;
    constexpr size_t SZ_ME = (size_t)Mq * Eq * 2;        // 8 MB
    u16*   Qb  = (u16*)  (ws + 0 * SZ_ME);
    u16*   Kb  = (u16*)  (ws + 1 * SZ_ME);
    u16*   KbT = (u16*)  (ws + 2 * SZ_ME);
    u16*   VbT = (u16*)  (ws + 3 * SZ_ME);
    u16*   Ob  = (u16*)  (ws + 4 * SZ_ME);
    float* KV  = (float*)(ws + 5 * SZ_ME);               // 16 MB f32
    u16*   STb = (u16*)  (ws + 5 * SZ_ME + (size_t)BH * NC * 4096 * 4);
    u16*   Xb  = (u16*)  (ws + 6 * SZ_ME + (size_t)BH * NC * 4096 * 4);
    u16*   Wb0 = (u16*)  (ws + 7 * SZ_ME + (size_t)BH * NC * 4096 * 4);
    // Wb0 layout: [Wq | Wk | Wv | Wo], each 1024*1024 bf16 (QKV part is one [3072][1024] matrix)
    u16* Wqkvb = Wb0;
    u16* Wob   = Wb0 + (size_t)3 * Eq * Eq;

    // 1) bf16 conversions (x; 4 weights in one launch)
    {
        int n4x = Mq * Eq / 4;
        cvt_kernel<<<dim3((n4x + 255) / 256), dim3(256), 0, stream>>>(x, Xb, n4x);
        int n4w = Eq * Eq / 4;
        cvt4_kernel<<<dim3((n4w + 255) / 256, 4), dim3(256), 0, stream>>>(
            Wq, Wk, Wv, Wo, Wb0, n4w);
    }

    // 2) fused QKV projection (M=4096, N=3072, K=1024)
    gemm_kernel<0><<<dim3(24, 32), dim3(256), 0, stream>>>(
        Xb, Wqkvb, bq, bk, bv, Qb, Kb, KbT, VbT, nullptr);

    // 3) attention
    chunk_kv_kernel<<<dim3(BH * NC), dim3(64), 0, stream>>>(KbT, VbT, KV);
    scan_kernel<<<dim3(BH), dim3(256), 0, stream>>>(KV, STb);
    attn_kernel<<<dim3(BH * NC), dim3(64), 0, stream>>>(Qb, Kb, VbT, STb, Ob);

    // 4) output projection (f32 out)
    gemm_kernel<1><<<dim3(8, 32), dim3(256), 0, stream>>>(
        Ob, Wob, bo, nullptr, nullptr, nullptr, nullptr, nullptr, nullptr, out);
}

// Round 3
// 102.932 us; speedup vs baseline: 1.7121x; 1.1795x over previous
//
#include <hip/hip_runtime.h>
#include <hip/hip_bf16.h>
#include <cmath>

typedef unsigned short u16;
typedef __bf16 bf16x8 __attribute__((ext_vector_type(8)));
typedef float  f32x4  __attribute__((ext_vector_type(4)));
typedef float  f4     __attribute__((ext_vector_type(4)));
typedef u16    us4    __attribute__((ext_vector_type(4)));

#define DEVFN __device__ __forceinline__

static constexpr int Bq = 2, Nq = 2048, Eq = 1024;
static constexpr int Mq = Bq * Nq;        // 4096 tokens
static constexpr int CHK = 64;            // attention chunk
static constexpr int NC  = Nq / CHK;      // 32 chunks
static constexpr int BH  = Bq * 16;       // 32

DEVFN u16 f2b(float f) {                  // f32 -> bf16 (RNE), finite inputs
    union { float f; unsigned int u; } x; x.f = f;
    unsigned int r = x.u + 0x7fffu + ((x.u >> 16) & 1u);
    return (u16)(r >> 16);
}

DEVFN void gl_lds16(const u16* g, u16* l) {  // async 16B global->LDS (dest: wave base + lane*16)
    __builtin_amdgcn_global_load_lds(
        (const __attribute__((address_space(1))) unsigned int*)(g),
        (__attribute__((address_space(3))) unsigned int*)(l),
        16, 0, 0);
}

// swizzled fragment read: LDS[R][S] (64 u16/row) holds global slot S^(R&7).
// want global 16B-slot G of row R -> read slot G^(R&7).
DEVFN const bf16x8* frag(const u16* S, int R, int G) {
    return reinterpret_cast<const bf16x8*>(&S[R * 64 + ((G ^ (R & 7)) << 3)]);
}

// ---------------- f32 -> bf16 bulk converts ----------------
__global__ __launch_bounds__(256) void cvt_kernel(const float* __restrict__ src,
                                                  u16* __restrict__ dst, int n4) {
    int i = blockIdx.x * 256 + threadIdx.x;
    if (i < n4) {
        f4 v = *reinterpret_cast<const f4*>(&src[(size_t)i * 4]);
        us4 p; p[0] = f2b(v[0]); p[1] = f2b(v[1]); p[2] = f2b(v[2]); p[3] = f2b(v[3]);
        *reinterpret_cast<us4*>(&dst[(size_t)i * 4]) = p;
    }
}

__global__ __launch_bounds__(256) void cvt4_kernel(const float* __restrict__ s0,
                                                   const float* __restrict__ s1,
                                                   const float* __restrict__ s2,
                                                   const float* __restrict__ s3,
                                                   u16* __restrict__ dst, int n4each) {
    const int which = blockIdx.y;
    const float* s = (which == 0) ? s0 : (which == 1) ? s1 : (which == 2) ? s2 : s3;
    int i = blockIdx.x * 256 + threadIdx.x;
    if (i < n4each) {
        f4 v = *reinterpret_cast<const f4*>(&s[(size_t)i * 4]);
        us4 p; p[0] = f2b(v[0]); p[1] = f2b(v[1]); p[2] = f2b(v[2]); p[3] = f2b(v[3]);
        *reinterpret_cast<us4*>(&dst[((size_t)which * n4each + i) * 4]) = p;
    }
}

// ---------------- GEMM, BK=64, global_load_lds w16, both-sides swizzle ----------------
// out[m][n] = act(sum_k X[m][k]*W[n][k] + bias[n])
// MODE 0: fused QKV, BM=128, N=3072. seg: 0=q (elu+1 -> Qb), 1=k (-> Kb + KbT), 2=v (-> VbT)
// MODE 1: O-projection, BM=64, N=1024, f32 output (512 blocks -> 2 blocks/CU)
template<int MODE>
__global__ __launch_bounds__(256)
void gemm_kernel(const u16* __restrict__ X, const u16* __restrict__ W,
                 const float* __restrict__ b0, const float* __restrict__ b1,
                 const float* __restrict__ b2,
                 u16* __restrict__ Qb, u16* __restrict__ Kb, u16* __restrict__ KbT,
                 u16* __restrict__ VbT, float* __restrict__ outF)
{
    constexpr int BM = (MODE == 0) ? 128 : 64;
    constexpr int MI = BM / 32;                 // A-fragments per wave: 4 or 2
    __shared__ u16 As[BM * 64];                 // linear rows of 64 u16 (128B)
    __shared__ u16 Bs[128 * 64];
    const int tid  = threadIdx.x;
    const int m0   = blockIdx.y * BM, n0 = blockIdx.x * 128;
    const int wid  = tid >> 6, lane = tid & 63;
    const int wr   = (wid >> 1) * (BM / 2), wc = (wid & 1) * 64;
    const int fr   = lane & 15, fq = lane >> 4;

    // staging: thread t covers 16B; row=tid>>3, slot=tid&7; fetch global slot (slot^(row&7))
    const int srow = tid >> 3;
    const int sw   = (tid & 7) ^ (srow & 7);
    const u16* gA = X + (size_t)(m0 + srow) * 1024 + sw * 8;
    const u16* gB = W + (size_t)(n0 + srow) * 1024 + sw * 8;
    u16* lA = As + wid * 512;                   // per-wave 1KB chunk of each 4KB call
    u16* lB = Bs + wid * 512;

    f32x4 acc[MI][4] = {};

    for (int k0 = 0; k0 < 1024; k0 += 64) {
        __syncthreads();
#pragma unroll
        for (int i = 0; i < BM / 32; ++i)
            gl_lds16(gA + k0 + i * 32 * 1024, lA + i * 2048);
#pragma unroll
        for (int i = 0; i < 4; ++i)
            gl_lds16(gB + k0 + i * 32 * 1024, lB + i * 2048);
        __syncthreads();

#pragma unroll
        for (int kk = 0; kk < 2; ++kk) {        // per-kk loads keep VGPR low
            bf16x8 af[MI], bfv[4];
#pragma unroll
            for (int mi = 0; mi < MI; ++mi)
                af[mi] = *frag(As, wr + mi * 16 + fr, kk * 4 + fq);
#pragma unroll
            for (int ni = 0; ni < 4; ++ni)
                bfv[ni] = *frag(Bs, wc + ni * 16 + fr, kk * 4 + fq);
#pragma unroll
            for (int mi = 0; mi < MI; ++mi)
#pragma unroll
                for (int ni = 0; ni < 4; ++ni)
                    acc[mi][ni] = __builtin_amdgcn_mfma_f32_16x16x32_bf16(
                        af[mi], bfv[ni], acc[mi][ni], 0, 0, 0);
        }
    }

    if (MODE == 0) {
        const int seg = n0 >> 10;                          // 0=q 1=k 2=v
        const float* bp = (seg == 0) ? b0 : (seg == 1) ? b1 : b2;
#pragma unroll
        for (int mi = 0; mi < MI; ++mi)
#pragma unroll
            for (int ni = 0; ni < 4; ++ni) {
                const int nl    = (n0 & 1023) + wc + ni * 16 + fr;
                const int mbase = m0 + wr + mi * 16 + fq * 4;
                const float bn  = bp[nl];
                float vr[4];
#pragma unroll
                for (int r = 0; r < 4; ++r) {
                    float v = acc[mi][ni][r] + bn;
                    if (seg < 2) v = (v > 0.f) ? (v + 1.f) : __expf(v);  // elu+1
                    vr[r] = v;
                }
                if (seg == 0) {
#pragma unroll
                    for (int r = 0; r < 4; ++r)
                        Qb[(size_t)(mbase + r) * 1024 + nl] = f2b(vr[r]);
                } else {
                    us4 pk;
#pragma unroll
                    for (int r = 0; r < 4; ++r) pk[r] = f2b(vr[r]);
                    const int bb = mbase >> 11, nt = mbase & 2047;
                    const int hh = nl >> 6,     dd = nl & 63;
                    u16* T = (seg == 1) ? KbT : VbT;
                    *reinterpret_cast<us4*>(
                        &T[((size_t)(bb * 16 + hh) * 64 + dd) * 2048 + nt]) = pk;
                    if (seg == 1) {
#pragma unroll
                        for (int r = 0; r < 4; ++r)
                            Kb[(size_t)(mbase + r) * 1024 + nl] = f2b(vr[r]);
                    }
                }
            }
    } else {
#pragma unroll
        for (int mi = 0; mi < MI; ++mi)
#pragma unroll
            for (int ni = 0; ni < 4; ++ni) {
                const int n     = n0 + wc + ni * 16 + fr;
                const int mbase = m0 + wr + mi * 16 + fq * 4;
                const float bn  = b0[n];
#pragma unroll
                for (int r = 0; r < 4; ++r)
                    outF[(size_t)(mbase + r) * 1024 + n] = acc[mi][ni][r] + bn;
            }
    }
}

// ---------------- per-chunk KV^T = v_chunk^T @ k_chunk: KVT[de][dk] ----------------
__global__ __launch_bounds__(64)
void chunk_kv_kernel(const u16* __restrict__ KbT, const u16* __restrict__ VbT,
                     float* __restrict__ KVT)
{
    const int blk = blockIdx.x;          // bh*NC + c
    const int bh = blk >> 5, c = blk & 31;
    const int lane = threadIdx.x;
    const int fr = lane & 15, fq = lane >> 4, fk = fq * 8;
    const u16* kt = KbT + (size_t)bh * 64 * 2048;
    const u16* vt = VbT + (size_t)bh * 64 * 2048;

    bf16x8 a[4][2], b[4][2];             // a = V rows (de), b = K rows (dk)
#pragma unroll
    for (int mi = 0; mi < 4; ++mi)
#pragma unroll
        for (int kh = 0; kh < 2; ++kh)
            a[mi][kh] = *reinterpret_cast<const bf16x8*>(
                &vt[(size_t)(mi * 16 + fr) * 2048 + c * 64 + kh * 32 + fk]);
#pragma unroll
    for (int ni = 0; ni < 4; ++ni)
#pragma unroll
        for (int kh = 0; kh < 2; ++kh)
            b[ni][kh] = *reinterpret_cast<const bf16x8*>(
                &kt[(size_t)(ni * 16 + fr) * 2048 + c * 64 + kh * 32 + fk]);

    f32x4 acc[4][4] = {};
#pragma unroll
    for (int mi = 0; mi < 4; ++mi)
#pragma unroll
        for (int ni = 0; ni < 4; ++ni)
#pragma unroll
            for (int kh = 0; kh < 2; ++kh)
                acc[mi][ni] = __builtin_amdgcn_mfma_f32_16x16x32_bf16(
                    a[mi][kh], b[ni][kh], acc[mi][ni], 0, 0, 0);

    float* out = KVT + (size_t)blk * 4096;   // [de][dk]
#pragma unroll
    for (int mi = 0; mi < 4; ++mi)
#pragma unroll
        for (int ni = 0; ni < 4; ++ni)
#pragma unroll
            for (int r = 0; r < 4; ++r)
                out[(mi * 16 + fq * 4 + r) * 64 + ni * 16 + fr] = acc[mi][ni][r];
}

// ---------------- elementwise exclusive scan over chunks (already transposed) ----------------
__global__ __launch_bounds__(256)
void scan_kernel(const float* __restrict__ KVT, u16* __restrict__ STb)
{
    const int bh = blockIdx.x >> 4, sl = blockIdx.x & 15;
    const int el = sl * 256 + threadIdx.x;              // element of [de][dk]
    const float* src = KVT + (size_t)bh * NC * 4096 + el;
    u16*         dst = STb + (size_t)bh * NC * 4096 + el;
    float run = 0.f;
#pragma unroll 4
    for (int c = 0; c < NC; ++c) {
        dst[(size_t)c * 4096] = f2b(run);               // exclusive prefix
        run += src[(size_t)c * 4096];
    }
}

// ---------------- per-chunk attention output ----------------
__global__ __launch_bounds__(64)
void attn_kernel(const u16* __restrict__ Qb, const u16* __restrict__ Kb,
                 const u16* __restrict__ VbT, const u16* __restrict__ STb,
                 u16* __restrict__ Ob)
{
    __shared__ u16 P[64 * 72];   // stride 72 u16 = 144B: 16B-aligned, 2-way banks
    const int blk = blockIdx.x;
    const int bh = blk >> 5, c = blk & 31;
    const int b = bh >> 4, h = bh & 15;
    const int lane = threadIdx.x;
    const int fr = lane & 15, fq = lane >> 4, fk = fq * 8;
    const int tok0 = b * 2048 + c * 64;

    bf16x8 qa[4][2];
#pragma unroll
    for (int mi = 0; mi < 4; ++mi)
#pragma unroll
        for (int kh = 0; kh < 2; ++kh)
            qa[mi][kh] = *reinterpret_cast<const bf16x8*>(
                &Qb[(size_t)(tok0 + mi * 16 + fr) * 1024 + h * 64 + kh * 32 + fk]);

    // P = causal-mask(q @ k^T) -> LDS bf16
    {
        bf16x8 kb[4][2];
#pragma unroll
        for (int si = 0; si < 4; ++si)
#pragma unroll
            for (int kh = 0; kh < 2; ++kh)
                kb[si][kh] = *reinterpret_cast<const bf16x8*>(
                    &Kb[(size_t)(tok0 + si * 16 + fr) * 1024 + h * 64 + kh * 32 + fk]);
        f32x4 p[4][4] = {};
#pragma unroll
        for (int mi = 0; mi < 4; ++mi)
#pragma unroll
            for (int si = 0; si < 4; ++si)
#pragma unroll
                for (int kh = 0; kh < 2; ++kh)
                    p[mi][si] = __builtin_amdgcn_mfma_f32_16x16x32_bf16(
                        qa[mi][kh], kb[si][kh], p[mi][si], 0, 0, 0);
#pragma unroll
        for (int mi = 0; mi < 4; ++mi)
#pragma unroll
            for (int si = 0; si < 4; ++si)
#pragma unroll
                for (int r = 0; r < 4; ++r) {
                    int t = mi * 16 + fq * 4 + r;
                    int s = si * 16 + fr;
                    float v = (s <= t) ? p[mi][si][r] : 0.0f;
                    P[t * 72 + s] = f2b(v);
                }
    }
    __syncthreads();

    f32x4 acc[4][4] = {};
    // acc = q @ ST   (STb[de][dk], dk-contiguous)
    {
        const u16* st = STb + (size_t)blk * 4096;
        bf16x8 sb[4][2];
#pragma unroll
        for (int ni = 0; ni < 4; ++ni)
#pragma unroll
            for (int kh = 0; kh < 2; ++kh)
                sb[ni][kh] = *reinterpret_cast<const bf16x8*>(
                    &st[(ni * 16 + fr) * 64 + kh * 32 + fk]);
#pragma unroll
        for (int mi = 0; mi < 4; ++mi)
#pragma unroll
            for (int ni = 0; ni < 4; ++ni)
#pragma unroll
                for (int kh = 0; kh < 2; ++kh)
                    acc[mi][ni] = __builtin_amdgcn_mfma_f32_16x16x32_bf16(
                        qa[mi][kh], sb[ni][kh], acc[mi][ni], 0, 0, 0);
    }
    // acc += P @ v
    {
        const u16* vt = VbT + (size_t)bh * 64 * 2048;
#pragma unroll
        for (int sh = 0; sh < 2; ++sh) {
            bf16x8 pa[4], vb[4];
#pragma unroll
            for (int mi = 0; mi < 4; ++mi)
                pa[mi] = *reinterpret_cast<const bf16x8*>(
                    &P[(mi * 16 + fr) * 72 + sh * 32 + fk]);
#pragma unroll
            for (int ni = 0; ni < 4; ++ni)
                vb[ni] = *reinterpret_cast<const bf16x8*>(
                    &vt[(size_t)(ni * 16 + fr) * 2048 + c * 64 + sh * 32 + fk]);
#pragma unroll
            for (int mi = 0; mi < 4; ++mi)
#pragma unroll
                for (int ni = 0; ni < 4; ++ni)
                    acc[mi][ni] = __builtin_amdgcn_mfma_f32_16x16x32_bf16(
                        pa[mi], vb[ni], acc[mi][ni], 0, 0, 0);
        }
    }
    // write token-major bf16 O
#pragma unroll
    for (int mi = 0; mi < 4; ++mi)
#pragma unroll
        for (int ni = 0; ni < 4; ++ni)
#pragma unroll
            for (int r = 0; r < 4; ++r) {
                int t = tok0 + mi * 16 + fq * 4 + r;
                int n = h * 64 + ni * 16 + fr;
                Ob[(size_t)t * 1024 + n] = f2b(acc[mi][ni][r]);
            }
}

extern "C" void kernel_launch(void* const* d_in, const int* in_sizes, int n_in,
                              void* d_out, int out_size, void* d_ws, size_t ws_size,
                              hipStream_t stream)
{
    (void)in_sizes; (void)n_in; (void)out_size; (void)ws_size;
    const float* x  = (const float*)d_in[0];
    const float* Wq = (const float*)d_in[1];
    const float* bq = (const float*)d_in[2];
    const float* Wk = (const float*)d_in[3];
    const float* bk = (const float*)d_in[4];
    const float* Wv = (const float*)d_in[5];
    const float* bv = (const float*)d_in[6];
    const float* Wo = (const float*)d_in[7];
    const float* bo = (const float*)d_in[8];
    float* out = (float*)d_out;

    char* ws = (char*)d_ws;
    constexpr size_t SZ_ME = (size_t)Mq * Eq * 2;        // 8 MB
    u16*   Qb  = (u16*)  (ws + 0 * SZ_ME);
    u16*   Kb  = (u16*)  (ws + 1 * SZ_ME);
    u16*   KbT = (u16*)  (ws + 2 * SZ_ME);
    u16*   VbT = (u16*)  (ws + 3 * SZ_ME);
    u16*   Ob  = (u16*)  (ws + 4 * SZ_ME);
    float* KVT = (float*)(ws + 5 * SZ_ME);               // 16 MB f32
    u16*   STb = (u16*)  (ws + 5 * SZ_ME + (size_t)BH * NC * 4096 * 4);
    u16*   Xb  = (u16*)  (ws + 6 * SZ_ME + (size_t)BH * NC * 4096 * 4);
    u16*   Wb0 = (u16*)  (ws + 7 * SZ_ME + (size_t)BH * NC * 4096 * 4);
    u16* Wqkvb = Wb0;                                    // [Wq|Wk|Wv] as [3072][1024]
    u16* Wob   = Wb0 + (size_t)3 * Eq * Eq;

    // 1) bf16 conversions
    {
        int n4x = Mq * Eq / 4;
        cvt_kernel<<<dim3((n4x + 255) / 256), dim3(256), 0, stream>>>(x, Xb, n4x);
        int n4w = Eq * Eq / 4;
        cvt4_kernel<<<dim3((n4w + 255) / 256, 4), dim3(256), 0, stream>>>(
            Wq, Wk, Wv, Wo, Wb0, n4w);
    }

    // 2) fused QKV projection (M=4096, N=3072, K=1024), BM=128
    gemm_kernel<0><<<dim3(24, 32), dim3(256), 0, stream>>>(
        Xb, Wqkvb, bq, bk, bv, Qb, Kb, KbT, VbT, nullptr);

    // 3) attention
    chunk_kv_kernel<<<dim3(BH * NC), dim3(64), 0, stream>>>(KbT, VbT, KVT);
    scan_kernel<<<dim3(BH * 16), dim3(256), 0, stream>>>(KVT, STb);
    attn_kernel<<<dim3(BH * NC), dim3(64), 0, stream>>>(Qb, Kb, VbT, STb, Ob);

    // 4) output projection (M=4096, N=1024), BM=64 -> 512 blocks (2/CU)
    gemm_kernel<1><<<dim3(8, 64), dim3(256), 0, stream>>>(
        Ob, Wob, bo, nullptr, nullptr, nullptr, nullptr, nullptr, nullptr, out);
}